// Round 13
// baseline (831.318 us; speedup 1.0000x reference)
//
#include <hip/hip_runtime.h>

#define D_MODEL 1024
#define D_FF    4096
#define N_EXP   8
#define BM 128
#define BN 128
#define BK 32

typedef __attribute__((ext_vector_type(8))) short bf16x8;
typedef __attribute__((ext_vector_type(4))) float f32x4;
typedef unsigned int u32;

__device__ __forceinline__ unsigned short f2bf(float f) {
  union { float f; unsigned u; } v; v.f = f;
  unsigned r = v.u + 0x7FFFu + ((v.u >> 16) & 1u);
  return (unsigned short)(r >> 16);
}

__device__ __forceinline__ void gl_lds16(const void* g, void* l) {
  __builtin_amdgcn_global_load_lds((const __attribute__((address_space(1))) u32*)g,
                                   (__attribute__((address_space(3))) u32*)l, 16, 0, 0);
}

// ---------------- merged transpose+convert: W1 and W2 -> bf16 [e][n][k] ----------------
// z<8: W1 expert z (K=D_MODEL, N=D_FF, kb=y*64, nb=x*64)
// z>=8: W2 expert z-8 (K=D_FF, N=D_MODEL, kb=x*64, nb=y*64)
__global__ __launch_bounds__(256)
void transpose_convert_all(const float* __restrict__ W1, const float* __restrict__ W2,
                           unsigned short* __restrict__ w1t, unsigned short* __restrict__ w2t) {
  __shared__ u32 s32k[32][65];  // [k/2][n]
  int z = blockIdx.z;
  const float* se;
  unsigned short* de;
  int Ksub, Nsrc, kb, nb;
  if (z < 8) {
    Ksub = D_MODEL; Nsrc = D_FF;
    kb = blockIdx.y * 64; nb = blockIdx.x * 64;
    se = W1 + (size_t)z * D_MODEL * D_FF;
    de = w1t + (size_t)z * D_FF * D_MODEL;
  } else {
    Ksub = D_FF; Nsrc = D_MODEL;
    kb = blockIdx.x * 64; nb = blockIdx.y * 64;
    se = W2 + (size_t)(z - 8) * D_FF * D_MODEL;
    de = w2t + (size_t)(z - 8) * D_MODEL * D_FF;
  }
  se += (size_t)kb * Nsrc + nb;
  de += (size_t)nb * Ksub + kb;
  int tid = threadIdx.x;
  int kh = tid >> 4;
  int n4 = (tid & 15) * 4;
  #pragma unroll
  for (int p = 0; p < 2; p++) {
    int k = kh * 2 + p * 32;
    float4 v0 = *(const float4*)(se + (size_t)k * Nsrc + n4);
    float4 v1 = *(const float4*)(se + (size_t)(k + 1) * Nsrc + n4);
    #pragma unroll
    for (int j = 0; j < 4; j++) {
      u32 pk = (u32)f2bf(((const float*)&v0)[j]) |
               ((u32)f2bf(((const float*)&v1)[j]) << 16);
      s32k[k >> 1][n4 + j] = pk;
    }
  }
  __syncthreads();
  #pragma unroll
  for (int c = 0; c < 2; c++) {
    int id = tid + c * 256;
    int n = id >> 3, kc = id & 7;
    uint4 o;
    o.x = s32k[kc * 4 + 0][n];
    o.y = s32k[kc * 4 + 1][n];
    o.z = s32k[kc * 4 + 2][n];
    o.w = s32k[kc * 4 + 3][n];
    *(uint4*)(de + (size_t)n * Ksub + kc * 8) = o;
  }
}

// ---------------- gating (+ fused x->bf16 convert): 1 wave per token ----------------
__global__ void gating_kernel(const float* __restrict__ x,
                              const float* __restrict__ Wg,
                              const float* __restrict__ bg,
                              float* __restrict__ gate_out,
                              unsigned short* __restrict__ xb,
                              int* __restrict__ cnt,
                              int* __restrict__ tokIdx,
                              float* __restrict__ tokW, int T) {
  int wv = threadIdx.x >> 6, lane = threadIdx.x & 63;
  int t = blockIdx.x * 4 + wv;
  if (t >= T) return;
  const float* xr = x + (size_t)t * D_MODEL + lane * 16;
  float acc[N_EXP];
  #pragma unroll
  for (int e = 0; e < N_EXP; e++) acc[e] = 0.f;
  ushort4 xc[4];
  #pragma unroll
  for (int q = 0; q < 4; q++) {
    float4 xv = *(const float4*)(xr + q * 4);
    xc[q].x = f2bf(xv.x); xc[q].y = f2bf(xv.y);
    xc[q].z = f2bf(xv.z); xc[q].w = f2bf(xv.w);
    #pragma unroll
    for (int r = 0; r < 4; r++) {
      float xs = ((const float*)&xv)[r];
      const float* wrow = Wg + (size_t)(lane * 16 + q * 4 + r) * N_EXP;
      float4 wa = *(const float4*)wrow;
      float4 wb = *(const float4*)(wrow + 4);
      acc[0] += xs * wa.x; acc[1] += xs * wa.y; acc[2] += xs * wa.z; acc[3] += xs * wa.w;
      acc[4] += xs * wb.x; acc[5] += xs * wb.y; acc[6] += xs * wb.z; acc[7] += xs * wb.w;
    }
  }
  unsigned short* xbr = xb + (size_t)t * D_MODEL + lane * 16;
  #pragma unroll
  for (int q = 0; q < 4; q++) *(ushort4*)(xbr + q * 4) = xc[q];
  #pragma unroll
  for (int off = 32; off > 0; off >>= 1) {
    #pragma unroll
    for (int e = 0; e < N_EXP; e++) acc[e] += __shfl_xor(acc[e], off);
  }
  if (lane == 0) {
    float l[N_EXP], p[N_EXP];
    float m = -1e30f;
    #pragma unroll
    for (int e = 0; e < N_EXP; e++) { l[e] = acc[e] + bg[e]; m = fmaxf(m, l[e]); }
    float s = 0.f;
    #pragma unroll
    for (int e = 0; e < N_EXP; e++) { p[e] = __expf(l[e] - m); s += p[e]; }
    float inv = 1.f / s;
    #pragma unroll
    for (int e = 0; e < N_EXP; e++) { p[e] *= inv; gate_out[(size_t)t * N_EXP + e] = p[e]; }
    int e1 = 0;
    #pragma unroll
    for (int e = 1; e < N_EXP; e++) if (p[e] > p[e1]) e1 = e;
    int e2 = (e1 == 0) ? 1 : 0;
    #pragma unroll
    for (int e = 0; e < N_EXP; e++) if (e != e1 && p[e] > p[e2]) e2 = e;
    int pos = atomicAdd(cnt + e1, 1);
    tokIdx[(size_t)e1 * T + pos] = t; tokW[(size_t)e1 * T + pos] = p[e1];
    pos = atomicAdd(cnt + e2, 1);
    tokIdx[(size_t)e2 * T + pos] = t; tokW[(size_t)e2 * T + pos] = p[e2];
  }
}

// ---------------- schedule: build row-tile table ----------------
__global__ void schedule_kernel(const int* __restrict__ cnt, int* __restrict__ meta,
                                int* __restrict__ tE, int* __restrict__ tB,
                                int* __restrict__ tV, int T, int maxTiles) {
  if (threadIdx.x != 0 || blockIdx.x != 0) return;
  int t = 0;
  for (int e = 0; e < N_EXP; e++) {
    int c = cnt[e];
    for (int r = 0; r < c && t < maxTiles; r += BM) {
      tE[t] = e; tB[t] = e * T + r; tV[t] = min(BM, c - r); t++;
    }
  }
  meta[0] = t;
}

// ======== pipelined BK=32 K-loop machinery ========
#define STAGE(b, kt) { _Pragma("unroll") for (int p_ = 0; p_ < 2; p_++) { \
    gl_lds16(srcA[p_] + (size_t)(kt) * BK, &LDSU[(b) * 8192 + (w * 32 + p_ * 16) * 32]); \
    gl_lds16(srcB[p_] + (size_t)(kt) * BK, &LDSU[(b) * 8192 + 4096 + (w * 32 + p_ * 16) * 32]); } }

#define COMPUTE(b) { \
    bf16x8 ra[4], rb[4]; \
    _Pragma("unroll") for (int m_ = 0; m_ < 4; m_++) { \
      int row_ = wr * 64 + m_ * 16 + l15; \
      ra[m_] = *(const bf16x8*)&LDSU[(b) * 8192 + row_ * 32 + (((l4 + (row_ >> 1)) & 3) << 3)]; } \
    _Pragma("unroll") for (int n_ = 0; n_ < 4; n_++) { \
      int rb_ = wc * 64 + n_ * 16 + l15; \
      rb[n_] = *(const bf16x8*)&LDSU[(b) * 8192 + 4096 + rb_ * 32 + (((l4 + (rb_ >> 1)) & 3) << 3)]; } \
    _Pragma("unroll") for (int m_ = 0; m_ < 4; m_++) \
      _Pragma("unroll") for (int n_ = 0; n_ < 4; n_++) \
        acc[m_][n_] = __builtin_amdgcn_mfma_f32_16x16x32_bf16(ra[m_], rb[n_], acc[m_][n_], 0, 0, 0); }

#define BAR() { __builtin_amdgcn_s_barrier(); asm volatile("" ::: "memory"); }
#define WAITVM(N) asm volatile("s_waitcnt vmcnt(" #N ")" ::: "memory");

// 3-buffer, depth-2. NT must satisfy (NT-2) % 3 == 0 (holds for 32).
#define PIPE3(NT) \
  STAGE(0, 0); STAGE(1, 1); \
  for (int it = 0; it < ((NT) - 2) / 3; it++) { \
    int kt = 3 * it; \
    STAGE(2, kt + 2); WAITVM(8); BAR(); COMPUTE(0); BAR(); \
    STAGE(0, kt + 3); WAITVM(8); BAR(); COMPUTE(1); BAR(); \
    STAGE(1, kt + 4); WAITVM(8); BAR(); COMPUTE(2); BAR(); \
  } \
  WAITVM(4); BAR(); COMPUTE(0); BAR(); \
  WAITVM(0); BAR(); COMPUTE(1);

// ---------------- GEMM1: h = relu(x_bf16 @ W1 + b1)  (cb-major works, 3-buf) ----------------
__global__ __launch_bounds__(256)
void gemm1_kernel(const unsigned short* __restrict__ xb,
                  const unsigned short* __restrict__ w1t,  // [e][D_FF][D_MODEL] bf16
                  const float* __restrict__ b1,
                  const int* __restrict__ meta,
                  const int* __restrict__ tE, const int* __restrict__ tB,
                  const int* __restrict__ tV, const int* __restrict__ tokIdx,
                  unsigned short* __restrict__ h, int nT) {
  __shared__ unsigned short LDSU[24576];  // 48 KiB = 3 buffers

  int total = gridDim.x;
  int L = blockIdx.x;
  int q = total >> 3, r8 = total & 7;
  int xcd = L & 7, idx = L >> 3;
  int work = (xcd < r8) ? (xcd * (q + 1) + idx) : (r8 * (q + 1) + (xcd - r8) * q + idx);
  int cb = work / nT;
  int tile = work - cb * nT;
  if (tile >= meta[0]) return;
  int e = tE[tile], base = tB[tile], valid = tV[tile];
  int tid = threadIdx.x;

  int w = tid >> 6, lane = tid & 63;
  int wr = w >> 1, wc = w & 1;
  int l15 = lane & 15, l4 = lane >> 4;
  int lrow = lane >> 2, lch = lane & 3;

  const unsigned short* panel = w1t + (size_t)e * D_FF * D_MODEL;
  const unsigned short* srcA[2];
  const unsigned short* srcB[2];
  #pragma unroll
  for (int p = 0; p < 2; p++) {
    int r = w * 32 + p * 16 + lrow;
    int tok = tokIdx[base + (r < valid ? r : valid - 1)];
    int g = (lch - (r >> 1)) & 3;
    srcA[p] = xb + (size_t)tok * D_MODEL + g * 8;
    srcB[p] = panel + (size_t)(cb * BN + r) * D_MODEL + g * 8;
  }

  f32x4 acc[4][4];
  #pragma unroll
  for (int m = 0; m < 4; m++)
    #pragma unroll
    for (int n = 0; n < 4; n++) acc[m][n] = (f32x4){0.f, 0.f, 0.f, 0.f};

  PIPE3(D_MODEL / BK);  // 32

  #pragma unroll
  for (int n = 0; n < 4; n++) {
    int colc = cb * BN + wc * 64 + n * 16 + l15;
    float bias = b1[(size_t)e * D_FF + colc];
    #pragma unroll
    for (int m = 0; m < 4; m++) {
      #pragma unroll
      for (int r = 0; r < 4; r++) {
        int row = wr * 64 + m * 16 + l4 * 4 + r;
        float v = acc[m][n][r] + bias;
        v = v > 0.f ? v : 0.f;
        h[(size_t)(tile * BM + row) * D_FF + colc] = f2bf(v);
      }
    }
  }
}

// ---------------- GEMM2: out += w * (h @ W2 + b2)  (K-split 4, cb low bits, 3-buf) ----------------
__global__ __launch_bounds__(256)
void gemm2_kernel(const unsigned short* __restrict__ h,
                  const unsigned short* __restrict__ w2t,  // [e][D_MODEL][D_FF] bf16
                  const float* __restrict__ b2,
                  const int* __restrict__ meta,
                  const int* __restrict__ tE, const int* __restrict__ tB,
                  const int* __restrict__ tV, const int* __restrict__ tokIdx,
                  const float* __restrict__ tokW,
                  float* __restrict__ out) {
  __shared__ unsigned short LDSU[24576];  // 48 KiB = 3 buffers

  int total = gridDim.x;
  int L = blockIdx.x;
  int q = total >> 3, r8 = total & 7;
  int xcd = L & 7, idx = L >> 3;
  int work = (xcd < r8) ? (xcd * (q + 1) + idx) : (r8 * (q + 1) + (xcd - r8) * q + idx);
  int tile = work >> 5;           // tile | ks | cb  (cb lowest: 8 cb share h segment)
  int ks = (work >> 3) & 3;
  int cb = work & 7;
  if (tile >= meta[0]) return;
  int e = tE[tile], base = tB[tile], valid = tV[tile];
  int tid = threadIdx.x;

  int w = tid >> 6, lane = tid & 63;
  int wr = w >> 1, wc = w & 1;
  int l15 = lane & 15, l4 = lane >> 4;
  int lrow = lane >> 2, lch = lane & 3;

  const int ksOff = ks * (D_FF / 4);   // 1024 elements per split

  const unsigned short* panel = w2t + (size_t)e * D_MODEL * D_FF;
  const unsigned short* srcA[2];
  const unsigned short* srcB[2];
  #pragma unroll
  for (int p = 0; p < 2; p++) {
    int r = w * 32 + p * 16 + lrow;
    int g = (lch - (r >> 1)) & 3;
    srcA[p] = h + (size_t)(tile * BM + r) * D_FF + ksOff + g * 8;
    srcB[p] = panel + (size_t)(cb * BN + r) * D_FF + ksOff + g * 8;
  }

  f32x4 acc[4][4];
  #pragma unroll
  for (int m = 0; m < 4; m++)
    #pragma unroll
    for (int n = 0; n < 4; n++) acc[m][n] = (f32x4){0.f, 0.f, 0.f, 0.f};

  PIPE3(D_FF / 4 / BK);  // 32

  float biasv[4];
  int addBias = (ks == 0) ? 1 : 0;
  #pragma unroll
  for (int n = 0; n < 4; n++)
    biasv[n] = addBias ? b2[(size_t)e * D_MODEL + cb * BN + wc * 64 + n * 16 + l15] : 0.f;

  #pragma unroll
  for (int m = 0; m < 4; m++) {
    #pragma unroll
    for (int r = 0; r < 4; r++) {
      int row = wr * 64 + m * 16 + l4 * 4 + r;
      if (row < valid) {
        int tok = tokIdx[base + row];
        float wgt = tokW[base + row];
        float* orow = out + (size_t)tok * D_MODEL + cb * BN + wc * 64 + l15;
        #pragma unroll
        for (int n = 0; n < 4; n++)
          atomicAdd(orow + n * 16, (acc[m][n][r] + biasv[n]) * wgt);
      }
    }
  }
}

// ---------------- host ----------------
extern "C" void kernel_launch(void* const* d_in, const int* in_sizes, int n_in,
                              void* d_out, int out_size, void* d_ws, size_t ws_size,
                              hipStream_t stream) {
  const float* x  = (const float*)d_in[0];
  const float* W1 = (const float*)d_in[1];
  const float* b1 = (const float*)d_in[2];
  const float* W2 = (const float*)d_in[3];
  const float* b2 = (const float*)d_in[4];
  const float* Wg = (const float*)d_in[5];
  const float* bg = (const float*)d_in[6];

  int T = in_sizes[0] / D_MODEL;  // 8192
  float* out = (float*)d_out;
  float* gate_out = out + (size_t)T * D_MODEL;

  char* ws = (char*)d_ws;
  int* cnt  = (int*)(ws + 0);
  int* meta = (int*)(ws + 64);
  int* tE   = (int*)(ws + 128);
  int* tB   = (int*)(ws + 1024);
  int* tV   = (int*)(ws + 2048);
  size_t off = 4096;
  int* tokIdx = (int*)(ws + off);   off += (size_t)N_EXP * T * 4;
  float* tokW = (float*)(ws + off); off += (size_t)N_EXP * T * 4;
  unsigned short* xb = (unsigned short*)(ws + off); off += (size_t)T * D_MODEL * 2;
  off = (off + 255) & ~(size_t)255;

  int maxTiles = (2 * T) / BM + N_EXP;  // 136

  unsigned short* w1t = (unsigned short*)(ws + off); off += (size_t)N_EXP * D_MODEL * D_FF * 2;
  unsigned short* w2t = (unsigned short*)(ws + off); off += (size_t)N_EXP * D_MODEL * D_FF * 2;
  unsigned short* h   = (unsigned short*)(ws + off);

  hipMemsetAsync(d_out, 0, (size_t)T * D_MODEL * sizeof(float), stream);
  hipMemsetAsync(cnt, 0, N_EXP * sizeof(int), stream);

  gating_kernel<<<(T + 3) / 4, 256, 0, stream>>>(x, Wg, bg, gate_out, xb, cnt, tokIdx, tokW, T);
  schedule_kernel<<<1, 64, 0, stream>>>(cnt, meta, tE, tB, tV, T, maxTiles);

  transpose_convert_all<<<dim3(64, 16, 16), 256, 0, stream>>>(W1, W2, w1t, w2t);

  gemm1_kernel<<<maxTiles * (D_FF / BN), 256, 0, stream>>>(
      xb, w1t, b1, meta, tE, tB, tV, tokIdx, h, maxTiles);
  gemm2_kernel<<<maxTiles * (D_MODEL / BN) * 4, 256, 0, stream>>>(
      h, w2t, b2, meta, tE, tB, tV, tokIdx, tokW, out);
}

// Round 14
// 738.907 us; speedup vs baseline: 1.1251x; 1.1251x over previous
//
#include <hip/hip_runtime.h>

#define D_MODEL 1024
#define D_FF    4096
#define N_EXP   8
#define BM 128
#define BN 128
#define BK 32

typedef __attribute__((ext_vector_type(8))) short bf16x8;
typedef __attribute__((ext_vector_type(4))) float f32x4;
typedef unsigned int u32;

__device__ __forceinline__ unsigned short f2bf(float f) {
  union { float f; unsigned u; } v; v.f = f;
  unsigned r = v.u + 0x7FFFu + ((v.u >> 16) & 1u);
  return (unsigned short)(r >> 16);
}

__device__ __forceinline__ void gl_lds16(const void* g, void* l) {
  __builtin_amdgcn_global_load_lds((const __attribute__((address_space(1))) u32*)g,
                                   (__attribute__((address_space(3))) u32*)l, 16, 0, 0);
}

// ---------------- merged transpose+convert: W1 and W2 -> bf16 [e][n][k] ----------------
__global__ __launch_bounds__(256)
void transpose_convert_all(const float* __restrict__ W1, const float* __restrict__ W2,
                           unsigned short* __restrict__ w1t, unsigned short* __restrict__ w2t) {
  __shared__ u32 s32k[32][65];  // [k/2][n]
  int z = blockIdx.z;
  const float* se;
  unsigned short* de;
  int Ksub, Nsrc, kb, nb;
  if (z < 8) {
    Ksub = D_MODEL; Nsrc = D_FF;
    kb = blockIdx.y * 64; nb = blockIdx.x * 64;
    se = W1 + (size_t)z * D_MODEL * D_FF;
    de = w1t + (size_t)z * D_FF * D_MODEL;
  } else {
    Ksub = D_FF; Nsrc = D_MODEL;
    kb = blockIdx.x * 64; nb = blockIdx.y * 64;
    se = W2 + (size_t)(z - 8) * D_FF * D_MODEL;
    de = w2t + (size_t)(z - 8) * D_MODEL * D_FF;
  }
  se += (size_t)kb * Nsrc + nb;
  de += (size_t)nb * Ksub + kb;
  int tid = threadIdx.x;
  int kh = tid >> 4;
  int n4 = (tid & 15) * 4;
  #pragma unroll
  for (int p = 0; p < 2; p++) {
    int k = kh * 2 + p * 32;
    float4 v0 = *(const float4*)(se + (size_t)k * Nsrc + n4);
    float4 v1 = *(const float4*)(se + (size_t)(k + 1) * Nsrc + n4);
    #pragma unroll
    for (int j = 0; j < 4; j++) {
      u32 pk = (u32)f2bf(((const float*)&v0)[j]) |
               ((u32)f2bf(((const float*)&v1)[j]) << 16);
      s32k[k >> 1][n4 + j] = pk;
    }
  }
  __syncthreads();
  #pragma unroll
  for (int c = 0; c < 2; c++) {
    int id = tid + c * 256;
    int n = id >> 3, kc = id & 7;
    uint4 o;
    o.x = s32k[kc * 4 + 0][n];
    o.y = s32k[kc * 4 + 1][n];
    o.z = s32k[kc * 4 + 2][n];
    o.w = s32k[kc * 4 + 3][n];
    *(uint4*)(de + (size_t)n * Ksub + kc * 8) = o;
  }
}

// ---------------- gating (+ fused x->bf16 convert): 1 wave per token ----------------
__global__ void gating_kernel(const float* __restrict__ x,
                              const float* __restrict__ Wg,
                              const float* __restrict__ bg,
                              float* __restrict__ gate_out,
                              unsigned short* __restrict__ xb,
                              int* __restrict__ cnt,
                              int* __restrict__ tokIdx,
                              float* __restrict__ tokW, int T) {
  int wv = threadIdx.x >> 6, lane = threadIdx.x & 63;
  int t = blockIdx.x * 4 + wv;
  if (t >= T) return;
  const float* xr = x + (size_t)t * D_MODEL + lane * 16;
  float acc[N_EXP];
  #pragma unroll
  for (int e = 0; e < N_EXP; e++) acc[e] = 0.f;
  ushort4 xc[4];
  #pragma unroll
  for (int q = 0; q < 4; q++) {
    float4 xv = *(const float4*)(xr + q * 4);
    xc[q].x = f2bf(xv.x); xc[q].y = f2bf(xv.y);
    xc[q].z = f2bf(xv.z); xc[q].w = f2bf(xv.w);
    #pragma unroll
    for (int r = 0; r < 4; r++) {
      float xs = ((const float*)&xv)[r];
      const float* wrow = Wg + (size_t)(lane * 16 + q * 4 + r) * N_EXP;
      float4 wa = *(const float4*)wrow;
      float4 wb = *(const float4*)(wrow + 4);
      acc[0] += xs * wa.x; acc[1] += xs * wa.y; acc[2] += xs * wa.z; acc[3] += xs * wa.w;
      acc[4] += xs * wb.x; acc[5] += xs * wb.y; acc[6] += xs * wb.z; acc[7] += xs * wb.w;
    }
  }
  unsigned short* xbr = xb + (size_t)t * D_MODEL + lane * 16;
  #pragma unroll
  for (int q = 0; q < 4; q++) *(ushort4*)(xbr + q * 4) = xc[q];
  #pragma unroll
  for (int off = 32; off > 0; off >>= 1) {
    #pragma unroll
    for (int e = 0; e < N_EXP; e++) acc[e] += __shfl_xor(acc[e], off);
  }
  if (lane == 0) {
    float l[N_EXP], p[N_EXP];
    float m = -1e30f;
    #pragma unroll
    for (int e = 0; e < N_EXP; e++) { l[e] = acc[e] + bg[e]; m = fmaxf(m, l[e]); }
    float s = 0.f;
    #pragma unroll
    for (int e = 0; e < N_EXP; e++) { p[e] = __expf(l[e] - m); s += p[e]; }
    float inv = 1.f / s;
    #pragma unroll
    for (int e = 0; e < N_EXP; e++) { p[e] *= inv; gate_out[(size_t)t * N_EXP + e] = p[e]; }
    int e1 = 0;
    #pragma unroll
    for (int e = 1; e < N_EXP; e++) if (p[e] > p[e1]) e1 = e;
    int e2 = (e1 == 0) ? 1 : 0;
    #pragma unroll
    for (int e = 0; e < N_EXP; e++) if (e != e1 && p[e] > p[e2]) e2 = e;
    int pos = atomicAdd(cnt + e1, 1);
    tokIdx[(size_t)e1 * T + pos] = t; tokW[(size_t)e1 * T + pos] = p[e1];
    pos = atomicAdd(cnt + e2, 1);
    tokIdx[(size_t)e2 * T + pos] = t; tokW[(size_t)e2 * T + pos] = p[e2];
  }
}

// ---------------- schedule: build row-tile table ----------------
__global__ void schedule_kernel(const int* __restrict__ cnt, int* __restrict__ meta,
                                int* __restrict__ tE, int* __restrict__ tB,
                                int* __restrict__ tV, int T, int maxTiles) {
  if (threadIdx.x != 0 || blockIdx.x != 0) return;
  int t = 0;
  for (int e = 0; e < N_EXP; e++) {
    int c = cnt[e];
    for (int r = 0; r < c && t < maxTiles; r += BM) {
      tE[t] = e; tB[t] = e * T + r; tV[t] = min(BM, c - r); t++;
    }
  }
  meta[0] = t;
}

// ======== pipelined BK=32 K-loop machinery ========
#define STAGE(b, kt) { _Pragma("unroll") for (int p_ = 0; p_ < 2; p_++) { \
    gl_lds16(srcA[p_] + (size_t)(kt) * BK, &LDSU[(b) * 8192 + (w * 32 + p_ * 16) * 32]); \
    gl_lds16(srcB[p_] + (size_t)(kt) * BK, &LDSU[(b) * 8192 + 4096 + (w * 32 + p_ * 16) * 32]); } }

#define COMPUTE(b) { \
    bf16x8 ra[4], rb[4]; \
    _Pragma("unroll") for (int m_ = 0; m_ < 4; m_++) { \
      int row_ = wr * 64 + m_ * 16 + l15; \
      ra[m_] = *(const bf16x8*)&LDSU[(b) * 8192 + row_ * 32 + (((l4 + (row_ >> 1)) & 3) << 3)]; } \
    _Pragma("unroll") for (int n_ = 0; n_ < 4; n_++) { \
      int rb_ = wc * 64 + n_ * 16 + l15; \
      rb[n_] = *(const bf16x8*)&LDSU[(b) * 8192 + 4096 + rb_ * 32 + (((l4 + (rb_ >> 1)) & 3) << 3)]; } \
    _Pragma("unroll") for (int m_ = 0; m_ < 4; m_++) \
      _Pragma("unroll") for (int n_ = 0; n_ < 4; n_++) \
        acc[m_][n_] = __builtin_amdgcn_mfma_f32_16x16x32_bf16(ra[m_], rb[n_], acc[m_][n_], 0, 0, 0); }

#define BAR() { __builtin_amdgcn_s_barrier(); asm volatile("" ::: "memory"); }
#define WAITVM(N) asm volatile("s_waitcnt vmcnt(" #N ")" ::: "memory");

// 3-buffer, depth-2. NT must satisfy (NT-2) % 3 == 0 (holds for 32 and 128).
#define PIPE3(NT) \
  STAGE(0, 0); STAGE(1, 1); \
  for (int it = 0; it < ((NT) - 2) / 3; it++) { \
    int kt = 3 * it; \
    STAGE(2, kt + 2); WAITVM(8); BAR(); COMPUTE(0); BAR(); \
    STAGE(0, kt + 3); WAITVM(8); BAR(); COMPUTE(1); BAR(); \
    STAGE(1, kt + 4); WAITVM(8); BAR(); COMPUTE(2); BAR(); \
  } \
  WAITVM(4); BAR(); COMPUTE(0); BAR(); \
  WAITVM(0); BAR(); COMPUTE(1);

// ---------------- GEMM1: h = relu(x_bf16 @ W1 + b1)  (cb-major works, 3-buf) ----------------
__global__ __launch_bounds__(256)
void gemm1_kernel(const unsigned short* __restrict__ xb,
                  const unsigned short* __restrict__ w1t,  // [e][D_FF][D_MODEL] bf16
                  const float* __restrict__ b1,
                  const int* __restrict__ meta,
                  const int* __restrict__ tE, const int* __restrict__ tB,
                  const int* __restrict__ tV, const int* __restrict__ tokIdx,
                  unsigned short* __restrict__ h, int nT) {
  __shared__ unsigned short LDSU[24576];  // 48 KiB = 3 buffers

  int total = gridDim.x;
  int L = blockIdx.x;
  int q = total >> 3, r8 = total & 7;
  int xcd = L & 7, idx = L >> 3;
  int work = (xcd < r8) ? (xcd * (q + 1) + idx) : (r8 * (q + 1) + (xcd - r8) * q + idx);
  int cb = work / nT;
  int tile = work - cb * nT;
  if (tile >= meta[0]) return;
  int e = tE[tile], base = tB[tile], valid = tV[tile];
  int tid = threadIdx.x;

  int w = tid >> 6, lane = tid & 63;
  int wr = w >> 1, wc = w & 1;
  int l15 = lane & 15, l4 = lane >> 4;
  int lrow = lane >> 2, lch = lane & 3;

  const unsigned short* panel = w1t + (size_t)e * D_FF * D_MODEL;
  const unsigned short* srcA[2];
  const unsigned short* srcB[2];
  #pragma unroll
  for (int p = 0; p < 2; p++) {
    int r = w * 32 + p * 16 + lrow;
    int tok = tokIdx[base + (r < valid ? r : valid - 1)];
    int g = (lch - (r >> 1)) & 3;
    srcA[p] = xb + (size_t)tok * D_MODEL + g * 8;
    srcB[p] = panel + (size_t)(cb * BN + r) * D_MODEL + g * 8;
  }

  f32x4 acc[4][4];
  #pragma unroll
  for (int m = 0; m < 4; m++)
    #pragma unroll
    for (int n = 0; n < 4; n++) acc[m][n] = (f32x4){0.f, 0.f, 0.f, 0.f};

  PIPE3(D_MODEL / BK);  // 32

  #pragma unroll
  for (int n = 0; n < 4; n++) {
    int colc = cb * BN + wc * 64 + n * 16 + l15;
    float bias = b1[(size_t)e * D_FF + colc];
    #pragma unroll
    for (int m = 0; m < 4; m++) {
      #pragma unroll
      for (int r = 0; r < 4; r++) {
        int row = wr * 64 + m * 16 + l4 * 4 + r;
        float v = acc[m][n][r] + bias;
        v = v > 0.f ? v : 0.f;
        h[(size_t)(tile * BM + row) * D_FF + colc] = f2bf(v);
      }
    }
  }
}

// ---------------- GEMM2: out += w * (h @ W2 + b2)  (tile-major, full-K, 3-buf) ----------------
__global__ __launch_bounds__(256)
void gemm2_kernel(const unsigned short* __restrict__ h,
                  const unsigned short* __restrict__ w2t,  // [e][D_MODEL][D_FF] bf16
                  const float* __restrict__ b2,
                  const int* __restrict__ meta,
                  const int* __restrict__ tE, const int* __restrict__ tB,
                  const int* __restrict__ tV, const int* __restrict__ tokIdx,
                  const float* __restrict__ tokW,
                  float* __restrict__ out) {
  __shared__ unsigned short LDSU[24576];  // 48 KiB = 3 buffers

  int total = gridDim.x;
  int L = blockIdx.x;
  int q = total >> 3, r8 = total & 7;
  int xcd = L & 7, idx = L >> 3;
  int work = (xcd < r8) ? (xcd * (q + 1) + idx) : (r8 * (q + 1) + (xcd - r8) * q + idx);
  int tile = work >> 3;          // ncol = D_MODEL/BN = 8
  int cb = work & 7;
  if (tile >= meta[0]) return;
  int e = tE[tile], base = tB[tile], valid = tV[tile];
  int tid = threadIdx.x;

  int w = tid >> 6, lane = tid & 63;
  int wr = w >> 1, wc = w & 1;
  int l15 = lane & 15, l4 = lane >> 4;
  int lrow = lane >> 2, lch = lane & 3;

  const unsigned short* panel = w2t + (size_t)e * D_MODEL * D_FF;
  const unsigned short* srcA[2];
  const unsigned short* srcB[2];
  #pragma unroll
  for (int p = 0; p < 2; p++) {
    int r = w * 32 + p * 16 + lrow;
    int g = (lch - (r >> 1)) & 3;
    srcA[p] = h + (size_t)(tile * BM + r) * D_FF + g * 8;
    srcB[p] = panel + (size_t)(cb * BN + r) * D_FF + g * 8;
  }

  f32x4 acc[4][4];
  #pragma unroll
  for (int m = 0; m < 4; m++)
    #pragma unroll
    for (int n = 0; n < 4; n++) acc[m][n] = (f32x4){0.f, 0.f, 0.f, 0.f};

  PIPE3(D_FF / BK);  // 128

  float biasv[4];
  #pragma unroll
  for (int n = 0; n < 4; n++)
    biasv[n] = b2[(size_t)e * D_MODEL + cb * BN + wc * 64 + n * 16 + l15];

  #pragma unroll
  for (int m = 0; m < 4; m++) {
    #pragma unroll
    for (int r = 0; r < 4; r++) {
      int row = wr * 64 + m * 16 + l4 * 4 + r;
      if (row < valid) {
        int tok = tokIdx[base + row];
        float wgt = tokW[base + row];
        float* orow = out + (size_t)tok * D_MODEL + cb * BN + wc * 64 + l15;
        #pragma unroll
        for (int n = 0; n < 4; n++)
          atomicAdd(orow + n * 16, (acc[m][n][r] + biasv[n]) * wgt);
      }
    }
  }
}

// ---------------- host ----------------
extern "C" void kernel_launch(void* const* d_in, const int* in_sizes, int n_in,
                              void* d_out, int out_size, void* d_ws, size_t ws_size,
                              hipStream_t stream) {
  const float* x  = (const float*)d_in[0];
  const float* W1 = (const float*)d_in[1];
  const float* b1 = (const float*)d_in[2];
  const float* W2 = (const float*)d_in[3];
  const float* b2 = (const float*)d_in[4];
  const float* Wg = (const float*)d_in[5];
  const float* bg = (const float*)d_in[6];

  int T = in_sizes[0] / D_MODEL;  // 8192
  float* out = (float*)d_out;
  float* gate_out = out + (size_t)T * D_MODEL;

  char* ws = (char*)d_ws;
  int* cnt  = (int*)(ws + 0);
  int* meta = (int*)(ws + 64);
  int* tE   = (int*)(ws + 128);
  int* tB   = (int*)(ws + 1024);
  int* tV   = (int*)(ws + 2048);
  size_t off = 4096;
  int* tokIdx = (int*)(ws + off);   off += (size_t)N_EXP * T * 4;
  float* tokW = (float*)(ws + off); off += (size_t)N_EXP * T * 4;
  unsigned short* xb = (unsigned short*)(ws + off); off += (size_t)T * D_MODEL * 2;
  off = (off + 255) & ~(size_t)255;

  int maxTiles = (2 * T) / BM + N_EXP;  // 136

  unsigned short* w1t = (unsigned short*)(ws + off); off += (size_t)N_EXP * D_MODEL * D_FF * 2;
  unsigned short* w2t = (unsigned short*)(ws + off); off += (size_t)N_EXP * D_MODEL * D_FF * 2;
  unsigned short* h   = (unsigned short*)(ws + off);

  hipMemsetAsync(d_out, 0, (size_t)T * D_MODEL * sizeof(float), stream);
  hipMemsetAsync(cnt, 0, N_EXP * sizeof(int), stream);

  gating_kernel<<<(T + 3) / 4, 256, 0, stream>>>(x, Wg, bg, gate_out, xb, cnt, tokIdx, tokW, T);
  schedule_kernel<<<1, 64, 0, stream>>>(cnt, meta, tE, tB, tV, T, maxTiles);

  transpose_convert_all<<<dim3(64, 16, 16), 256, 0, stream>>>(W1, W2, w1t, w2t);

  gemm1_kernel<<<maxTiles * (D_FF / BN), 256, 0, stream>>>(
      xb, w1t, b1, meta, tE, tB, tV, tokIdx, h, maxTiles);
  gemm2_kernel<<<maxTiles * (D_MODEL / BN), 256, 0, stream>>>(
      h, w2t, b2, meta, tE, tB, tV, tokIdx, tokW, out);
}

// Round 15
// 710.800 us; speedup vs baseline: 1.1696x; 1.0395x over previous
//
#include <hip/hip_runtime.h>

#define D_MODEL 1024
#define D_FF    4096
#define N_EXP   8
#define BM 128
#define BN 128
#define BK 32

typedef __attribute__((ext_vector_type(8))) short bf16x8;
typedef __attribute__((ext_vector_type(4))) float f32x4;
typedef unsigned int u32;

__device__ __forceinline__ unsigned short f2bf(float f) {
  union { float f; unsigned u; } v; v.f = f;
  unsigned r = v.u + 0x7FFFu + ((v.u >> 16) & 1u);
  return (unsigned short)(r >> 16);
}

__device__ __forceinline__ void gl_lds16(const void* g, void* l) {
  __builtin_amdgcn_global_load_lds((const __attribute__((address_space(1))) u32*)g,
                                   (__attribute__((address_space(3))) u32*)l, 16, 0, 0);
}

// ---------------- merged transpose+convert: W1 and W2 -> bf16 [e][n][k] ----------------
__global__ __launch_bounds__(256)
void transpose_convert_all(const float* __restrict__ W1, const float* __restrict__ W2,
                           unsigned short* __restrict__ w1t, unsigned short* __restrict__ w2t) {
  __shared__ u32 s32k[32][65];  // [k/2][n]
  int z = blockIdx.z;
  const float* se;
  unsigned short* de;
  int Ksub, Nsrc, kb, nb;
  if (z < 8) {
    Ksub = D_MODEL; Nsrc = D_FF;
    kb = blockIdx.y * 64; nb = blockIdx.x * 64;
    se = W1 + (size_t)z * D_MODEL * D_FF;
    de = w1t + (size_t)z * D_FF * D_MODEL;
  } else {
    Ksub = D_FF; Nsrc = D_MODEL;
    kb = blockIdx.x * 64; nb = blockIdx.y * 64;
    se = W2 + (size_t)(z - 8) * D_FF * D_MODEL;
    de = w2t + (size_t)(z - 8) * D_MODEL * D_FF;
  }
  se += (size_t)kb * Nsrc + nb;
  de += (size_t)nb * Ksub + kb;
  int tid = threadIdx.x;
  int kh = tid >> 4;
  int n4 = (tid & 15) * 4;
  #pragma unroll
  for (int p = 0; p < 2; p++) {
    int k = kh * 2 + p * 32;
    float4 v0 = *(const float4*)(se + (size_t)k * Nsrc + n4);
    float4 v1 = *(const float4*)(se + (size_t)(k + 1) * Nsrc + n4);
    #pragma unroll
    for (int j = 0; j < 4; j++) {
      u32 pk = (u32)f2bf(((const float*)&v0)[j]) |
               ((u32)f2bf(((const float*)&v1)[j]) << 16);
      s32k[k >> 1][n4 + j] = pk;
    }
  }
  __syncthreads();
  #pragma unroll
  for (int c = 0; c < 2; c++) {
    int id = tid + c * 256;
    int n = id >> 3, kc = id & 7;
    uint4 o;
    o.x = s32k[kc * 4 + 0][n];
    o.y = s32k[kc * 4 + 1][n];
    o.z = s32k[kc * 4 + 2][n];
    o.w = s32k[kc * 4 + 3][n];
    *(uint4*)(de + (size_t)n * Ksub + kc * 8) = o;
  }
}

// ---------------- gating (+ fused x->bf16 convert): 1 wave per token ----------------
__global__ void gating_kernel(const float* __restrict__ x,
                              const float* __restrict__ Wg,
                              const float* __restrict__ bg,
                              float* __restrict__ gate_out,
                              unsigned short* __restrict__ xb,
                              int* __restrict__ cnt,
                              int* __restrict__ tokIdx,
                              float* __restrict__ tokW, int T) {
  int wv = threadIdx.x >> 6, lane = threadIdx.x & 63;
  int t = blockIdx.x * 4 + wv;
  if (t >= T) return;
  const float* xr = x + (size_t)t * D_MODEL + lane * 16;
  float acc[N_EXP];
  #pragma unroll
  for (int e = 0; e < N_EXP; e++) acc[e] = 0.f;
  ushort4 xc[4];
  #pragma unroll
  for (int q = 0; q < 4; q++) {
    float4 xv = *(const float4*)(xr + q * 4);
    xc[q].x = f2bf(xv.x); xc[q].y = f2bf(xv.y);
    xc[q].z = f2bf(xv.z); xc[q].w = f2bf(xv.w);
    #pragma unroll
    for (int r = 0; r < 4; r++) {
      float xs = ((const float*)&xv)[r];
      const float* wrow = Wg + (size_t)(lane * 16 + q * 4 + r) * N_EXP;
      float4 wa = *(const float4*)wrow;
      float4 wb = *(const float4*)(wrow + 4);
      acc[0] += xs * wa.x; acc[1] += xs * wa.y; acc[2] += xs * wa.z; acc[3] += xs * wa.w;
      acc[4] += xs * wb.x; acc[5] += xs * wb.y; acc[6] += xs * wb.z; acc[7] += xs * wb.w;
    }
  }
  unsigned short* xbr = xb + (size_t)t * D_MODEL + lane * 16;
  #pragma unroll
  for (int q = 0; q < 4; q++) *(ushort4*)(xbr + q * 4) = xc[q];
  #pragma unroll
  for (int off = 32; off > 0; off >>= 1) {
    #pragma unroll
    for (int e = 0; e < N_EXP; e++) acc[e] += __shfl_xor(acc[e], off);
  }
  if (lane == 0) {
    float l[N_EXP], p[N_EXP];
    float m = -1e30f;
    #pragma unroll
    for (int e = 0; e < N_EXP; e++) { l[e] = acc[e] + bg[e]; m = fmaxf(m, l[e]); }
    float s = 0.f;
    #pragma unroll
    for (int e = 0; e < N_EXP; e++) { p[e] = __expf(l[e] - m); s += p[e]; }
    float inv = 1.f / s;
    #pragma unroll
    for (int e = 0; e < N_EXP; e++) { p[e] *= inv; gate_out[(size_t)t * N_EXP + e] = p[e]; }
    int e1 = 0;
    #pragma unroll
    for (int e = 1; e < N_EXP; e++) if (p[e] > p[e1]) e1 = e;
    int e2 = (e1 == 0) ? 1 : 0;
    #pragma unroll
    for (int e = 0; e < N_EXP; e++) if (e != e1 && p[e] > p[e2]) e2 = e;
    int pos = atomicAdd(cnt + e1, 1);
    tokIdx[(size_t)e1 * T + pos] = t; tokW[(size_t)e1 * T + pos] = p[e1];
    pos = atomicAdd(cnt + e2, 1);
    tokIdx[(size_t)e2 * T + pos] = t; tokW[(size_t)e2 * T + pos] = p[e2];
  }
}

// ---------------- schedule: build row-tile table ----------------
__global__ void schedule_kernel(const int* __restrict__ cnt, int* __restrict__ meta,
                                int* __restrict__ tE, int* __restrict__ tB,
                                int* __restrict__ tV, int T, int maxTiles) {
  if (threadIdx.x != 0 || blockIdx.x != 0) return;
  int t = 0;
  for (int e = 0; e < N_EXP; e++) {
    int c = cnt[e];
    for (int r = 0; r < c && t < maxTiles; r += BM) {
      tE[t] = e; tB[t] = e * T + r; tV[t] = min(BM, c - r); t++;
    }
  }
  meta[0] = t;
}

// ======== 512-thread (8-wave) pipelined BK=32 K-loop ========
// Buffer b (ushort idx, base b*8192): A rows [0,4096), B rows [4096,8192).
// Row = 32 ushorts (64B, 4 chunks of 16B). LDS chunk c holds global chunk
// (c-(r>>1))&3; read at c_eff=(l4+(r>>1))&3 -> global chunk l4.
// STAGE: wave w stages A rows [w*16, w*16+16) and B rows likewise (1024B each,
// lane-contiguous dest matching gl_lds semantics). 2 loads/thread/STAGE.
#define STAGE(b, kt) { \
    gl_lds16(srcA0 + (size_t)(kt) * BK, &LDSU[(b) * 8192 + w * 512]); \
    gl_lds16(srcB0 + (size_t)(kt) * BK, &LDSU[(b) * 8192 + 4096 + w * 512]); }

#define COMPUTE(b) { \
    bf16x8 ra[4], rbv[2]; \
    _Pragma("unroll") for (int m_ = 0; m_ < 4; m_++) { \
      int row_ = wr * 64 + m_ * 16 + l15; \
      ra[m_] = *(const bf16x8*)&LDSU[(b) * 8192 + row_ * 32 + (((l4 + (row_ >> 1)) & 3) << 3)]; } \
    _Pragma("unroll") for (int n_ = 0; n_ < 2; n_++) { \
      int rb_ = wc * 32 + n_ * 16 + l15; \
      rbv[n_] = *(const bf16x8*)&LDSU[(b) * 8192 + 4096 + rb_ * 32 + (((l4 + (rb_ >> 1)) & 3) << 3)]; } \
    _Pragma("unroll") for (int m_ = 0; m_ < 4; m_++) \
      _Pragma("unroll") for (int n_ = 0; n_ < 2; n_++) \
        acc[m_][n_] = __builtin_amdgcn_mfma_f32_16x16x32_bf16(ra[m_], rbv[n_], acc[m_][n_], 0, 0, 0); }

#define BAR() { __builtin_amdgcn_s_barrier(); asm volatile("" ::: "memory"); }
#define WAITVM(N) asm volatile("s_waitcnt vmcnt(" #N ")" ::: "memory");

// 3-buffer, depth-2, 2 loads/thread/STAGE. (NT-2) % 3 == 0 (holds for 32, 128).
#define PIPE3(NT) \
  STAGE(0, 0); STAGE(1, 1); \
  for (int it = 0; it < ((NT) - 2) / 3; it++) { \
    int kt = 3 * it; \
    STAGE(2, kt + 2); WAITVM(4); BAR(); COMPUTE(0); BAR(); \
    STAGE(0, kt + 3); WAITVM(4); BAR(); COMPUTE(1); BAR(); \
    STAGE(1, kt + 4); WAITVM(4); BAR(); COMPUTE(2); BAR(); \
  } \
  WAITVM(2); BAR(); COMPUTE(0); BAR(); \
  WAITVM(0); BAR(); COMPUTE(1);

#define ACC_INIT() f32x4 acc[4][2]; \
  _Pragma("unroll") for (int m = 0; m < 4; m++) \
    _Pragma("unroll") for (int n = 0; n < 2; n++) acc[m][n] = (f32x4){0.f, 0.f, 0.f, 0.f};

// ---------------- GEMM1: h = relu(x_bf16 @ W1 + b1)  (cb-major, 512 thr, 3-buf) ----------------
__global__ __launch_bounds__(512)
void gemm1_kernel(const unsigned short* __restrict__ xb,
                  const unsigned short* __restrict__ w1t,  // [e][D_FF][D_MODEL] bf16
                  const float* __restrict__ b1,
                  const int* __restrict__ meta,
                  const int* __restrict__ tE, const int* __restrict__ tB,
                  const int* __restrict__ tV, const int* __restrict__ tokIdx,
                  unsigned short* __restrict__ h, int nT) {
  __shared__ unsigned short LDSU[24576];  // 48 KiB = 3 buffers

  int total = gridDim.x;
  int L = blockIdx.x;
  int q = total >> 3, r8 = total & 7;
  int xcd = L & 7, idx = L >> 3;
  int work = (xcd < r8) ? (xcd * (q + 1) + idx) : (r8 * (q + 1) + (xcd - r8) * q + idx);
  int cb = work / nT;
  int tile = work - cb * nT;
  if (tile >= meta[0]) return;
  int e = tE[tile], base = tB[tile], valid = tV[tile];
  int tid = threadIdx.x;

  int w = tid >> 6, lane = tid & 63;
  int wr = w >> 2, wc = w & 3;
  int l15 = lane & 15, l4 = lane >> 4;
  int sr = lane >> 2, lch = lane & 3;

  const unsigned short* panel = w1t + (size_t)e * D_FF * D_MODEL;
  int rS = w * 16 + sr;
  int tokS = tokIdx[base + (rS < valid ? rS : valid - 1)];
  int g = (lch - (rS >> 1)) & 3;
  const unsigned short* srcA0 = xb + (size_t)tokS * D_MODEL + g * 8;
  const unsigned short* srcB0 = panel + (size_t)(cb * BN + rS) * D_MODEL + g * 8;

  ACC_INIT();
  PIPE3(D_MODEL / BK);  // 32

  #pragma unroll
  for (int n = 0; n < 2; n++) {
    int colc = cb * BN + wc * 32 + n * 16 + l15;
    float bias = b1[(size_t)e * D_FF + colc];
    #pragma unroll
    for (int m = 0; m < 4; m++) {
      #pragma unroll
      for (int r = 0; r < 4; r++) {
        int row = wr * 64 + m * 16 + l4 * 4 + r;
        float v = acc[m][n][r] + bias;
        v = v > 0.f ? v : 0.f;
        h[(size_t)(tile * BM + row) * D_FF + colc] = f2bf(v);
      }
    }
  }
}

// ---------------- GEMM2: out += w * (h @ W2 + b2)  (tile-major, 512 thr, 3-buf) ----------------
__global__ __launch_bounds__(512)
void gemm2_kernel(const unsigned short* __restrict__ h,
                  const unsigned short* __restrict__ w2t,  // [e][D_MODEL][D_FF] bf16
                  const float* __restrict__ b2,
                  const int* __restrict__ meta,
                  const int* __restrict__ tE, const int* __restrict__ tB,
                  const int* __restrict__ tV, const int* __restrict__ tokIdx,
                  const float* __restrict__ tokW,
                  float* __restrict__ out) {
  __shared__ unsigned short LDSU[24576];  // 48 KiB = 3 buffers

  int total = gridDim.x;
  int L = blockIdx.x;
  int q = total >> 3, r8 = total & 7;
  int xcd = L & 7, idx = L >> 3;
  int work = (xcd < r8) ? (xcd * (q + 1) + idx) : (r8 * (q + 1) + (xcd - r8) * q + idx);
  int tile = work >> 3;          // ncol = D_MODEL/BN = 8
  int cb = work & 7;
  if (tile >= meta[0]) return;
  int e = tE[tile], base = tB[tile], valid = tV[tile];
  int tid = threadIdx.x;

  int w = tid >> 6, lane = tid & 63;
  int wr = w >> 2, wc = w & 3;
  int l15 = lane & 15, l4 = lane >> 4;
  int sr = lane >> 2, lch = lane & 3;

  const unsigned short* panel = w2t + (size_t)e * D_MODEL * D_FF;
  int rS = w * 16 + sr;
  int g = (lch - (rS >> 1)) & 3;
  const unsigned short* srcA0 = h + (size_t)(tile * BM + rS) * D_FF + g * 8;
  const unsigned short* srcB0 = panel + (size_t)(cb * BN + rS) * D_FF + g * 8;

  ACC_INIT();
  PIPE3(D_FF / BK);  // 128

  float biasv[2];
  #pragma unroll
  for (int n = 0; n < 2; n++)
    biasv[n] = b2[(size_t)e * D_MODEL + cb * BN + wc * 32 + n * 16 + l15];

  #pragma unroll
  for (int m = 0; m < 4; m++) {
    #pragma unroll
    for (int r = 0; r < 4; r++) {
      int row = wr * 64 + m * 16 + l4 * 4 + r;
      if (row < valid) {
        int tok = tokIdx[base + row];
        float wgt = tokW[base + row];
        float* orow = out + (size_t)tok * D_MODEL + cb * BN + wc * 32 + l15;
        #pragma unroll
        for (int n = 0; n < 2; n++)
          atomicAdd(orow + n * 16, (acc[m][n][r] + biasv[n]) * wgt);
      }
    }
  }
}

// ---------------- host ----------------
extern "C" void kernel_launch(void* const* d_in, const int* in_sizes, int n_in,
                              void* d_out, int out_size, void* d_ws, size_t ws_size,
                              hipStream_t stream) {
  const float* x  = (const float*)d_in[0];
  const float* W1 = (const float*)d_in[1];
  const float* b1 = (const float*)d_in[2];
  const float* W2 = (const float*)d_in[3];
  const float* b2 = (const float*)d_in[4];
  const float* Wg = (const float*)d_in[5];
  const float* bg = (const float*)d_in[6];

  int T = in_sizes[0] / D_MODEL;  // 8192
  float* out = (float*)d_out;
  float* gate_out = out + (size_t)T * D_MODEL;

  char* ws = (char*)d_ws;
  int* cnt  = (int*)(ws + 0);
  int* meta = (int*)(ws + 64);
  int* tE   = (int*)(ws + 128);
  int* tB   = (int*)(ws + 1024);
  int* tV   = (int*)(ws + 2048);
  size_t off = 4096;
  int* tokIdx = (int*)(ws + off);   off += (size_t)N_EXP * T * 4;
  float* tokW = (float*)(ws + off); off += (size_t)N_EXP * T * 4;
  unsigned short* xb = (unsigned short*)(ws + off); off += (size_t)T * D_MODEL * 2;
  off = (off + 255) & ~(size_t)255;

  int maxTiles = (2 * T) / BM + N_EXP;  // 136

  unsigned short* w1t = (unsigned short*)(ws + off); off += (size_t)N_EXP * D_MODEL * D_FF * 2;
  unsigned short* w2t = (unsigned short*)(ws + off); off += (size_t)N_EXP * D_MODEL * D_FF * 2;
  unsigned short* h   = (unsigned short*)(ws + off);

  hipMemsetAsync(d_out, 0, (size_t)T * D_MODEL * sizeof(float), stream);
  hipMemsetAsync(cnt, 0, N_EXP * sizeof(int), stream);

  gating_kernel<<<(T + 3) / 4, 256, 0, stream>>>(x, Wg, bg, gate_out, xb, cnt, tokIdx, tokW, T);
  schedule_kernel<<<1, 64, 0, stream>>>(cnt, meta, tE, tB, tV, T, maxTiles);

  transpose_convert_all<<<dim3(64, 16, 16), 256, 0, stream>>>(W1, W2, w1t, w2t);

  gemm1_kernel<<<maxTiles * (D_FF / BN), 512, 0, stream>>>(
      xb, w1t, b1, meta, tE, tB, tV, tokIdx, h, maxTiles);
  gemm2_kernel<<<maxTiles * (D_MODEL / BN), 512, 0, stream>>>(
      h, w2t, b2, meta, tE, tB, tV, tokIdx, tokW, out);
}

// Round 16
// 685.716 us; speedup vs baseline: 1.2123x; 1.0366x over previous
//
#include <hip/hip_runtime.h>

#define D_MODEL 1024
#define D_FF    4096
#define N_EXP   8
#define BM 128
#define BN 256
#define BK 32

typedef __attribute__((ext_vector_type(8))) short bf16x8;
typedef __attribute__((ext_vector_type(4))) float f32x4;
typedef unsigned int u32;

__device__ __forceinline__ unsigned short f2bf(float f) {
  union { float f; unsigned u; } v; v.f = f;
  unsigned r = v.u + 0x7FFFu + ((v.u >> 16) & 1u);
  return (unsigned short)(r >> 16);
}

__device__ __forceinline__ void gl_lds16(const void* g, void* l) {
  __builtin_amdgcn_global_load_lds((const __attribute__((address_space(1))) u32*)g,
                                   (__attribute__((address_space(3))) u32*)l, 16, 0, 0);
}

// ---------------- merged transpose+convert: W1 and W2 -> bf16 [e][n][k] ----------------
__global__ __launch_bounds__(256)
void transpose_convert_all(const float* __restrict__ W1, const float* __restrict__ W2,
                           unsigned short* __restrict__ w1t, unsigned short* __restrict__ w2t) {
  __shared__ u32 s32k[32][65];  // [k/2][n]
  int z = blockIdx.z;
  const float* se;
  unsigned short* de;
  int Ksub, Nsrc, kb, nb;
  if (z < 8) {
    Ksub = D_MODEL; Nsrc = D_FF;
    kb = blockIdx.y * 64; nb = blockIdx.x * 64;
    se = W1 + (size_t)z * D_MODEL * D_FF;
    de = w1t + (size_t)z * D_FF * D_MODEL;
  } else {
    Ksub = D_FF; Nsrc = D_MODEL;
    kb = blockIdx.x * 64; nb = blockIdx.y * 64;
    se = W2 + (size_t)(z - 8) * D_FF * D_MODEL;
    de = w2t + (size_t)(z - 8) * D_MODEL * D_FF;
  }
  se += (size_t)kb * Nsrc + nb;
  de += (size_t)nb * Ksub + kb;
  int tid = threadIdx.x;
  int kh = tid >> 4;
  int n4 = (tid & 15) * 4;
  #pragma unroll
  for (int p = 0; p < 2; p++) {
    int k = kh * 2 + p * 32;
    float4 v0 = *(const float4*)(se + (size_t)k * Nsrc + n4);
    float4 v1 = *(const float4*)(se + (size_t)(k + 1) * Nsrc + n4);
    #pragma unroll
    for (int j = 0; j < 4; j++) {
      u32 pk = (u32)f2bf(((const float*)&v0)[j]) |
               ((u32)f2bf(((const float*)&v1)[j]) << 16);
      s32k[k >> 1][n4 + j] = pk;
    }
  }
  __syncthreads();
  #pragma unroll
  for (int c = 0; c < 2; c++) {
    int id = tid + c * 256;
    int n = id >> 3, kc = id & 7;
    uint4 o;
    o.x = s32k[kc * 4 + 0][n];
    o.y = s32k[kc * 4 + 1][n];
    o.z = s32k[kc * 4 + 2][n];
    o.w = s32k[kc * 4 + 3][n];
    *(uint4*)(de + (size_t)n * Ksub + kc * 8) = o;
  }
}

// ---------------- gating (+ fused x->bf16 convert): 1 wave per token ----------------
__global__ void gating_kernel(const float* __restrict__ x,
                              const float* __restrict__ Wg,
                              const float* __restrict__ bg,
                              float* __restrict__ gate_out,
                              unsigned short* __restrict__ xb,
                              int* __restrict__ cnt,
                              int* __restrict__ tokIdx,
                              float* __restrict__ tokW, int T) {
  int wv = threadIdx.x >> 6, lane = threadIdx.x & 63;
  int t = blockIdx.x * 4 + wv;
  if (t >= T) return;
  const float* xr = x + (size_t)t * D_MODEL + lane * 16;
  float acc[N_EXP];
  #pragma unroll
  for (int e = 0; e < N_EXP; e++) acc[e] = 0.f;
  ushort4 xc[4];
  #pragma unroll
  for (int q = 0; q < 4; q++) {
    float4 xv = *(const float4*)(xr + q * 4);
    xc[q].x = f2bf(xv.x); xc[q].y = f2bf(xv.y);
    xc[q].z = f2bf(xv.z); xc[q].w = f2bf(xv.w);
    #pragma unroll
    for (int r = 0; r < 4; r++) {
      float xs = ((const float*)&xv)[r];
      const float* wrow = Wg + (size_t)(lane * 16 + q * 4 + r) * N_EXP;
      float4 wa = *(const float4*)wrow;
      float4 wb = *(const float4*)(wrow + 4);
      acc[0] += xs * wa.x; acc[1] += xs * wa.y; acc[2] += xs * wa.z; acc[3] += xs * wa.w;
      acc[4] += xs * wb.x; acc[5] += xs * wb.y; acc[6] += xs * wb.z; acc[7] += xs * wb.w;
    }
  }
  unsigned short* xbr = xb + (size_t)t * D_MODEL + lane * 16;
  #pragma unroll
  for (int q = 0; q < 4; q++) *(ushort4*)(xbr + q * 4) = xc[q];
  #pragma unroll
  for (int off = 32; off > 0; off >>= 1) {
    #pragma unroll
    for (int e = 0; e < N_EXP; e++) acc[e] += __shfl_xor(acc[e], off);
  }
  if (lane == 0) {
    float l[N_EXP], p[N_EXP];
    float m = -1e30f;
    #pragma unroll
    for (int e = 0; e < N_EXP; e++) { l[e] = acc[e] + bg[e]; m = fmaxf(m, l[e]); }
    float s = 0.f;
    #pragma unroll
    for (int e = 0; e < N_EXP; e++) { p[e] = __expf(l[e] - m); s += p[e]; }
    float inv = 1.f / s;
    #pragma unroll
    for (int e = 0; e < N_EXP; e++) { p[e] *= inv; gate_out[(size_t)t * N_EXP + e] = p[e]; }
    int e1 = 0;
    #pragma unroll
    for (int e = 1; e < N_EXP; e++) if (p[e] > p[e1]) e1 = e;
    int e2 = (e1 == 0) ? 1 : 0;
    #pragma unroll
    for (int e = 0; e < N_EXP; e++) if (e != e1 && p[e] > p[e2]) e2 = e;
    int pos = atomicAdd(cnt + e1, 1);
    tokIdx[(size_t)e1 * T + pos] = t; tokW[(size_t)e1 * T + pos] = p[e1];
    pos = atomicAdd(cnt + e2, 1);
    tokIdx[(size_t)e2 * T + pos] = t; tokW[(size_t)e2 * T + pos] = p[e2];
  }
}

// ---------------- schedule: build row-tile table ----------------
__global__ void schedule_kernel(const int* __restrict__ cnt, int* __restrict__ meta,
                                int* __restrict__ tE, int* __restrict__ tB,
                                int* __restrict__ tV, int T, int maxTiles) {
  if (threadIdx.x != 0 || blockIdx.x != 0) return;
  int t = 0;
  for (int e = 0; e < N_EXP; e++) {
    int c = cnt[e];
    for (int r = 0; r < c && t < maxTiles; r += BM) {
      tE[t] = e; tB[t] = e * T + r; tV[t] = min(BM, c - r); t++;
    }
  }
  meta[0] = t;
}

// ======== 512-thread, BM=128 x BN=256, acc[4][4], 3-buf BK=32 pipeline ========
// Buffer b (ushort idx, base b*12288): A rows [0,4096) (128x32), B rows [4096,12288) (256x32).
// Row = 32 ushorts (64B, 4 chunks of 16B). LDS chunk c holds global chunk
// (c-(r>>1))&3; read at c_eff=(l4+(r>>1))&3 -> global chunk l4.
// STAGE: 3 loads/thread (1 A-row pass, 2 B-row passes), lane-contiguous dests.
#define STAGE(b, kt) { \
    gl_lds16(srcA0 + (size_t)(kt) * BK, &LDSU[(b) * 12288 + w * 512]); \
    gl_lds16(srcB0 + (size_t)(kt) * BK, &LDSU[(b) * 12288 + 4096 + w * 1024]); \
    gl_lds16(srcB1 + (size_t)(kt) * BK, &LDSU[(b) * 12288 + 4096 + w * 1024 + 512]); }

#define COMPUTE(b) { \
    bf16x8 ra[4], rbv[4]; \
    _Pragma("unroll") for (int m_ = 0; m_ < 4; m_++) { \
      int row_ = wr * 64 + m_ * 16 + l15; \
      ra[m_] = *(const bf16x8*)&LDSU[(b) * 12288 + row_ * 32 + (((l4 + (row_ >> 1)) & 3) << 3)]; } \
    _Pragma("unroll") for (int n_ = 0; n_ < 4; n_++) { \
      int rb_ = wc * 64 + n_ * 16 + l15; \
      rbv[n_] = *(const bf16x8*)&LDSU[(b) * 12288 + 4096 + rb_ * 32 + (((l4 + (rb_ >> 1)) & 3) << 3)]; } \
    _Pragma("unroll") for (int m_ = 0; m_ < 4; m_++) \
      _Pragma("unroll") for (int n_ = 0; n_ < 4; n_++) \
        acc[m_][n_] = __builtin_amdgcn_mfma_f32_16x16x32_bf16(ra[m_], rbv[n_], acc[m_][n_], 0, 0, 0); }

#define BAR() { __builtin_amdgcn_s_barrier(); asm volatile("" ::: "memory"); }
#define WAITVM(N) asm volatile("s_waitcnt vmcnt(" #N ")" ::: "memory");

// 3-buffer, depth-2, 3 loads/thread/STAGE. (NT-2) % 3 == 0 (holds for 32, 128).
#define PIPE3(NT) \
  STAGE(0, 0); STAGE(1, 1); \
  for (int it = 0; it < ((NT) - 2) / 3; it++) { \
    int kt = 3 * it; \
    STAGE(2, kt + 2); WAITVM(6); BAR(); COMPUTE(0); BAR(); \
    STAGE(0, kt + 3); WAITVM(6); BAR(); COMPUTE(1); BAR(); \
    STAGE(1, kt + 4); WAITVM(6); BAR(); COMPUTE(2); BAR(); \
  } \
  WAITVM(3); BAR(); COMPUTE(0); BAR(); \
  WAITVM(0); BAR(); COMPUTE(1);

#define ACC_INIT() f32x4 acc[4][4]; \
  _Pragma("unroll") for (int m = 0; m < 4; m++) \
    _Pragma("unroll") for (int n = 0; n < 4; n++) acc[m][n] = (f32x4){0.f, 0.f, 0.f, 0.f};

// ---------------- GEMM1: h = relu(x_bf16 @ W1 + b1)  (cb-major, 512 thr, BN=256) ----------------
__global__ __launch_bounds__(512)
void gemm1_kernel(const unsigned short* __restrict__ xb,
                  const unsigned short* __restrict__ w1t,  // [e][D_FF][D_MODEL] bf16
                  const float* __restrict__ b1,
                  const int* __restrict__ meta,
                  const int* __restrict__ tE, const int* __restrict__ tB,
                  const int* __restrict__ tV, const int* __restrict__ tokIdx,
                  unsigned short* __restrict__ h, int nT) {
  __shared__ unsigned short LDSU[36864];  // 72 KiB = 3 x 24 KiB

  int total = gridDim.x;
  int L = blockIdx.x;
  int q = total >> 3, r8 = total & 7;
  int xcd = L & 7, idx = L >> 3;
  int work = (xcd < r8) ? (xcd * (q + 1) + idx) : (r8 * (q + 1) + (xcd - r8) * q + idx);
  int cb = work / nT;
  int tile = work - cb * nT;
  if (tile >= meta[0]) return;
  int e = tE[tile], base = tB[tile], valid = tV[tile];
  int tid = threadIdx.x;

  int w = tid >> 6, lane = tid & 63;
  int wr = w >> 2, wc = w & 3;
  int l15 = lane & 15, l4 = lane >> 4;
  int sr = lane >> 2, lch = lane & 3;

  const unsigned short* panel = w1t + (size_t)e * D_FF * D_MODEL;
  int rA = w * 16 + sr;
  int tokS = tokIdx[base + (rA < valid ? rA : valid - 1)];
  int gA = (lch - (rA >> 1)) & 3;
  const unsigned short* srcA0 = xb + (size_t)tokS * D_MODEL + gA * 8;
  int rB0 = w * 32 + sr;
  int gB0 = (lch - (rB0 >> 1)) & 3;
  const unsigned short* srcB0 = panel + (size_t)(cb * BN + rB0) * D_MODEL + gB0 * 8;
  int rB1 = w * 32 + 16 + sr;
  int gB1 = (lch - (rB1 >> 1)) & 3;
  const unsigned short* srcB1 = panel + (size_t)(cb * BN + rB1) * D_MODEL + gB1 * 8;

  ACC_INIT();
  PIPE3(D_MODEL / BK);  // 32

  #pragma unroll
  for (int n = 0; n < 4; n++) {
    int colc = cb * BN + wc * 64 + n * 16 + l15;
    float bias = b1[(size_t)e * D_FF + colc];
    #pragma unroll
    for (int m = 0; m < 4; m++) {
      #pragma unroll
      for (int r = 0; r < 4; r++) {
        int row = wr * 64 + m * 16 + l4 * 4 + r;
        float v = acc[m][n][r] + bias;
        v = v > 0.f ? v : 0.f;
        h[(size_t)(tile * BM + row) * D_FF + colc] = f2bf(v);
      }
    }
  }
}

// ---------------- GEMM2: out += w * (h @ W2 + b2)  (tile-major, 512 thr, BN=256) ----------------
__global__ __launch_bounds__(512)
void gemm2_kernel(const unsigned short* __restrict__ h,
                  const unsigned short* __restrict__ w2t,  // [e][D_MODEL][D_FF] bf16
                  const float* __restrict__ b2,
                  const int* __restrict__ meta,
                  const int* __restrict__ tE, const int* __restrict__ tB,
                  const int* __restrict__ tV, const int* __restrict__ tokIdx,
                  const float* __restrict__ tokW,
                  float* __restrict__ out) {
  __shared__ unsigned short LDSU[36864];  // 72 KiB

  int total = gridDim.x;
  int L = blockIdx.x;
  int q = total >> 3, r8 = total & 7;
  int xcd = L & 7, idx = L >> 3;
  int work = (xcd < r8) ? (xcd * (q + 1) + idx) : (r8 * (q + 1) + (xcd - r8) * q + idx);
  int tile = work >> 2;          // ncol = D_MODEL/BN = 4
  int cb = work & 3;
  if (tile >= meta[0]) return;
  int e = tE[tile], base = tB[tile], valid = tV[tile];
  int tid = threadIdx.x;

  int w = tid >> 6, lane = tid & 63;
  int wr = w >> 2, wc = w & 3;
  int l15 = lane & 15, l4 = lane >> 4;
  int sr = lane >> 2, lch = lane & 3;

  const unsigned short* panel = w2t + (size_t)e * D_MODEL * D_FF;
  int rA = w * 16 + sr;
  int gA = (lch - (rA >> 1)) & 3;
  const unsigned short* srcA0 = h + (size_t)(tile * BM + rA) * D_FF + gA * 8;
  int rB0 = w * 32 + sr;
  int gB0 = (lch - (rB0 >> 1)) & 3;
  const unsigned short* srcB0 = panel + (size_t)(cb * BN + rB0) * D_FF + gB0 * 8;
  int rB1 = w * 32 + 16 + sr;
  int gB1 = (lch - (rB1 >> 1)) & 3;
  const unsigned short* srcB1 = panel + (size_t)(cb * BN + rB1) * D_FF + gB1 * 8;

  ACC_INIT();
  PIPE3(D_FF / BK);  // 128

  float biasv[4];
  #pragma unroll
  for (int n = 0; n < 4; n++)
    biasv[n] = b2[(size_t)e * D_MODEL + cb * BN + wc * 64 + n * 16 + l15];

  #pragma unroll
  for (int m = 0; m < 4; m++) {
    #pragma unroll
    for (int r = 0; r < 4; r++) {
      int row = wr * 64 + m * 16 + l4 * 4 + r;
      if (row < valid) {
        int tok = tokIdx[base + row];
        float wgt = tokW[base + row];
        float* orow = out + (size_t)tok * D_MODEL + cb * BN + wc * 64 + l15;
        #pragma unroll
        for (int n = 0; n < 4; n++)
          atomicAdd(orow + n * 16, (acc[m][n][r] + biasv[n]) * wgt);
      }
    }
  }
}

// ---------------- host ----------------
extern "C" void kernel_launch(void* const* d_in, const int* in_sizes, int n_in,
                              void* d_out, int out_size, void* d_ws, size_t ws_size,
                              hipStream_t stream) {
  const float* x  = (const float*)d_in[0];
  const float* W1 = (const float*)d_in[1];
  const float* b1 = (const float*)d_in[2];
  const float* W2 = (const float*)d_in[3];
  const float* b2 = (const float*)d_in[4];
  const float* Wg = (const float*)d_in[5];
  const float* bg = (const float*)d_in[6];

  int T = in_sizes[0] / D_MODEL;  // 8192
  float* out = (float*)d_out;
  float* gate_out = out + (size_t)T * D_MODEL;

  char* ws = (char*)d_ws;
  int* cnt  = (int*)(ws + 0);
  int* meta = (int*)(ws + 64);
  int* tE   = (int*)(ws + 128);
  int* tB   = (int*)(ws + 1024);
  int* tV   = (int*)(ws + 2048);
  size_t off = 4096;
  int* tokIdx = (int*)(ws + off);   off += (size_t)N_EXP * T * 4;
  float* tokW = (float*)(ws + off); off += (size_t)N_EXP * T * 4;
  unsigned short* xb = (unsigned short*)(ws + off); off += (size_t)T * D_MODEL * 2;
  off = (off + 255) & ~(size_t)255;

  int maxTiles = (2 * T) / BM + N_EXP;  // 136

  unsigned short* w1t = (unsigned short*)(ws + off); off += (size_t)N_EXP * D_MODEL * D_FF * 2;
  unsigned short* w2t = (unsigned short*)(ws + off); off += (size_t)N_EXP * D_MODEL * D_FF * 2;
  unsigned short* h   = (unsigned short*)(ws + off);

  hipMemsetAsync(d_out, 0, (size_t)T * D_MODEL * sizeof(float), stream);
  hipMemsetAsync(cnt, 0, N_EXP * sizeof(int), stream);

  gating_kernel<<<(T + 3) / 4, 256, 0, stream>>>(x, Wg, bg, gate_out, xb, cnt, tokIdx, tokW, T);
  schedule_kernel<<<1, 64, 0, stream>>>(cnt, meta, tE, tB, tV, T, maxTiles);

  transpose_convert_all<<<dim3(64, 16, 16), 256, 0, stream>>>(W1, W2, w1t, w2t);

  gemm1_kernel<<<maxTiles * (D_FF / BN), 512, 0, stream>>>(
      xb, w1t, b1, meta, tE, tB, tV, tokIdx, h, maxTiles);
  gemm2_kernel<<<maxTiles * (D_MODEL / BN), 512, 0, stream>>>(
      h, w2t, b2, meta, tE, tB, tV, tokIdx, tokW, out);
}

// Round 17
// 680.662 us; speedup vs baseline: 1.2213x; 1.0074x over previous
//
#include <hip/hip_runtime.h>

#define D_MODEL 1024
#define D_FF    4096
#define N_EXP   8
#define BM 128
#define BN 256
#define BK 32

typedef __attribute__((ext_vector_type(8))) short bf16x8;
typedef __attribute__((ext_vector_type(4))) float f32x4;
typedef unsigned int u32;

__device__ __forceinline__ unsigned short f2bf(float f) {
  union { float f; unsigned u; } v; v.f = f;
  unsigned r = v.u + 0x7FFFu + ((v.u >> 16) & 1u);
  return (unsigned short)(r >> 16);
}

__device__ __forceinline__ void gl_lds16(const void* g, void* l) {
  __builtin_amdgcn_global_load_lds((const __attribute__((address_space(1))) u32*)g,
                                   (__attribute__((address_space(3))) u32*)l, 16, 0, 0);
}

// ---------------- transpose+convert, 256k x 64n per block ----------------
// Flat grid 4096: b<2048 -> W1 (kt=b&3, nt=(b>>2)&63, e=b>>8), Ksub=1024
//                 b>=2048 -> W2 (kt=b2&15, nt=(b2>>4)&15, e=b2>>8), Ksub=4096
// Phase1: 16 float4 loads/thread (deep in-flight), pack k-pairs to u32,
//         s32k[k/2][n] stride 65 (2-way banks, proven pattern).
// Phase2: per n-row, 32 lanes write 512B contiguous (uint4 each).
__global__ __launch_bounds__(256)
void transpose_convert_all(const float* __restrict__ W1, const float* __restrict__ W2,
                           unsigned short* __restrict__ w1t, unsigned short* __restrict__ w2t) {
  __shared__ u32 s32k[128][65];  // [k/2][n]
  int b = blockIdx.x;
  const float* se;
  unsigned short* de;
  int Ksub, Nsrc;
  if (b < 2048) {
    int kt = b & 3, nt = (b >> 2) & 63, e = b >> 8;
    Ksub = D_MODEL; Nsrc = D_FF;
    se = W1 + (size_t)e * D_MODEL * D_FF + (size_t)(kt * 256) * D_FF + nt * 64;
    de = w1t + (size_t)e * D_FF * D_MODEL + (size_t)(nt * 64) * D_MODEL + kt * 256;
  } else {
    int b2 = b - 2048;
    int kt = b2 & 15, nt = (b2 >> 4) & 15, e = b2 >> 8;
    Ksub = D_FF; Nsrc = D_MODEL;
    se = W2 + (size_t)e * D_FF * D_MODEL + (size_t)(kt * 256) * D_MODEL + nt * 64;
    de = w2t + (size_t)e * D_MODEL * D_FF + (size_t)(nt * 64) * D_FF + kt * 256;
  }
  int tid = threadIdx.x;
  int kh = tid >> 4;            // 0..15
  int n4 = (tid & 15) * 4;      // 0..60
  #pragma unroll
  for (int p = 0; p < 8; p++) {
    int k = kh * 2 + p * 32;    // even, 0..254
    float4 v0 = *(const float4*)(se + (size_t)k * Nsrc + n4);
    float4 v1 = *(const float4*)(se + (size_t)(k + 1) * Nsrc + n4);
    #pragma unroll
    for (int j = 0; j < 4; j++) {
      u32 pk = (u32)f2bf(((const float*)&v0)[j]) |
               ((u32)f2bf(((const float*)&v1)[j]) << 16);
      s32k[kh + p * 16][n4 + j] = pk;
    }
  }
  __syncthreads();
  #pragma unroll
  for (int c = 0; c < 8; c++) {
    int id = tid + c * 256;
    int n = id >> 5;            // 0..63
    int kc = id & 31;           // 0..31  (u32 cols kc*4..kc*4+3 = 128 u32)
    uint4 o;
    o.x = s32k[kc * 4 + 0][n];
    o.y = s32k[kc * 4 + 1][n];
    o.z = s32k[kc * 4 + 2][n];
    o.w = s32k[kc * 4 + 3][n];
    *(uint4*)(de + (size_t)n * Ksub + kc * 8) = o;
  }
}

// ---------------- gating (+ fused x->bf16 convert): 1 wave per token ----------------
__global__ void gating_kernel(const float* __restrict__ x,
                              const float* __restrict__ Wg,
                              const float* __restrict__ bg,
                              float* __restrict__ gate_out,
                              unsigned short* __restrict__ xb,
                              int* __restrict__ cnt,
                              int* __restrict__ tokIdx,
                              float* __restrict__ tokW, int T) {
  int wv = threadIdx.x >> 6, lane = threadIdx.x & 63;
  int t = blockIdx.x * 4 + wv;
  if (t >= T) return;
  const float* xr = x + (size_t)t * D_MODEL + lane * 16;
  float acc[N_EXP];
  #pragma unroll
  for (int e = 0; e < N_EXP; e++) acc[e] = 0.f;
  ushort4 xc[4];
  #pragma unroll
  for (int q = 0; q < 4; q++) {
    float4 xv = *(const float4*)(xr + q * 4);
    xc[q].x = f2bf(xv.x); xc[q].y = f2bf(xv.y);
    xc[q].z = f2bf(xv.z); xc[q].w = f2bf(xv.w);
    #pragma unroll
    for (int r = 0; r < 4; r++) {
      float xs = ((const float*)&xv)[r];
      const float* wrow = Wg + (size_t)(lane * 16 + q * 4 + r) * N_EXP;
      float4 wa = *(const float4*)wrow;
      float4 wb = *(const float4*)(wrow + 4);
      acc[0] += xs * wa.x; acc[1] += xs * wa.y; acc[2] += xs * wa.z; acc[3] += xs * wa.w;
      acc[4] += xs * wb.x; acc[5] += xs * wb.y; acc[6] += xs * wb.z; acc[7] += xs * wb.w;
    }
  }
  unsigned short* xbr = xb + (size_t)t * D_MODEL + lane * 16;
  #pragma unroll
  for (int q = 0; q < 4; q++) *(ushort4*)(xbr + q * 4) = xc[q];
  #pragma unroll
  for (int off = 32; off > 0; off >>= 1) {
    #pragma unroll
    for (int e = 0; e < N_EXP; e++) acc[e] += __shfl_xor(acc[e], off);
  }
  if (lane == 0) {
    float l[N_EXP], p[N_EXP];
    float m = -1e30f;
    #pragma unroll
    for (int e = 0; e < N_EXP; e++) { l[e] = acc[e] + bg[e]; m = fmaxf(m, l[e]); }
    float s = 0.f;
    #pragma unroll
    for (int e = 0; e < N_EXP; e++) { p[e] = __expf(l[e] - m); s += p[e]; }
    float inv = 1.f / s;
    #pragma unroll
    for (int e = 0; e < N_EXP; e++) { p[e] *= inv; gate_out[(size_t)t * N_EXP + e] = p[e]; }
    int e1 = 0;
    #pragma unroll
    for (int e = 1; e < N_EXP; e++) if (p[e] > p[e1]) e1 = e;
    int e2 = (e1 == 0) ? 1 : 0;
    #pragma unroll
    for (int e = 0; e < N_EXP; e++) if (e != e1 && p[e] > p[e2]) e2 = e;
    int pos = atomicAdd(cnt + e1, 1);
    tokIdx[(size_t)e1 * T + pos] = t; tokW[(size_t)e1 * T + pos] = p[e1];
    pos = atomicAdd(cnt + e2, 1);
    tokIdx[(size_t)e2 * T + pos] = t; tokW[(size_t)e2 * T + pos] = p[e2];
  }
}

// ---------------- schedule: build row-tile table ----------------
__global__ void schedule_kernel(const int* __restrict__ cnt, int* __restrict__ meta,
                                int* __restrict__ tE, int* __restrict__ tB,
                                int* __restrict__ tV, int T, int maxTiles) {
  if (threadIdx.x != 0 || blockIdx.x != 0) return;
  int t = 0;
  for (int e = 0; e < N_EXP; e++) {
    int c = cnt[e];
    for (int r = 0; r < c && t < maxTiles; r += BM) {
      tE[t] = e; tB[t] = e * T + r; tV[t] = min(BM, c - r); t++;
    }
  }
  meta[0] = t;
}

// ======== 512-thread, BM=128 x BN=256, acc[4][4], 3-buf BK=32 pipeline ========
#define STAGE(b, kt) { \
    gl_lds16(srcA0 + (size_t)(kt) * BK, &LDSU[(b) * 12288 + w * 512]); \
    gl_lds16(srcB0 + (size_t)(kt) * BK, &LDSU[(b) * 12288 + 4096 + w * 1024]); \
    gl_lds16(srcB1 + (size_t)(kt) * BK, &LDSU[(b) * 12288 + 4096 + w * 1024 + 512]); }

#define COMPUTE(b) { \
    bf16x8 ra[4], rbv[4]; \
    _Pragma("unroll") for (int m_ = 0; m_ < 4; m_++) { \
      int row_ = wr * 64 + m_ * 16 + l15; \
      ra[m_] = *(const bf16x8*)&LDSU[(b) * 12288 + row_ * 32 + (((l4 + (row_ >> 1)) & 3) << 3)]; } \
    _Pragma("unroll") for (int n_ = 0; n_ < 4; n_++) { \
      int rb_ = wc * 64 + n_ * 16 + l15; \
      rbv[n_] = *(const bf16x8*)&LDSU[(b) * 12288 + 4096 + rb_ * 32 + (((l4 + (rb_ >> 1)) & 3) << 3)]; } \
    _Pragma("unroll") for (int m_ = 0; m_ < 4; m_++) \
      _Pragma("unroll") for (int n_ = 0; n_ < 4; n_++) \
        acc[m_][n_] = __builtin_amdgcn_mfma_f32_16x16x32_bf16(ra[m_], rbv[n_], acc[m_][n_], 0, 0, 0); }

#define BAR() { __builtin_amdgcn_s_barrier(); asm volatile("" ::: "memory"); }
#define WAITVM(N) asm volatile("s_waitcnt vmcnt(" #N ")" ::: "memory");

#define PIPE3(NT) \
  STAGE(0, 0); STAGE(1, 1); \
  for (int it = 0; it < ((NT) - 2) / 3; it++) { \
    int kt = 3 * it; \
    STAGE(2, kt + 2); WAITVM(6); BAR(); COMPUTE(0); BAR(); \
    STAGE(0, kt + 3); WAITVM(6); BAR(); COMPUTE(1); BAR(); \
    STAGE(1, kt + 4); WAITVM(6); BAR(); COMPUTE(2); BAR(); \
  } \
  WAITVM(3); BAR(); COMPUTE(0); BAR(); \
  WAITVM(0); BAR(); COMPUTE(1);

#define ACC_INIT() f32x4 acc[4][4]; \
  _Pragma("unroll") for (int m = 0; m < 4; m++) \
    _Pragma("unroll") for (int n = 0; n < 4; n++) acc[m][n] = (f32x4){0.f, 0.f, 0.f, 0.f};

// ---------------- GEMM1: h = relu(x_bf16 @ W1 + b1)  (cb-major, 512 thr, BN=256) ----------------
__global__ __launch_bounds__(512)
void gemm1_kernel(const unsigned short* __restrict__ xb,
                  const unsigned short* __restrict__ w1t,  // [e][D_FF][D_MODEL] bf16
                  const float* __restrict__ b1,
                  const int* __restrict__ meta,
                  const int* __restrict__ tE, const int* __restrict__ tB,
                  const int* __restrict__ tV, const int* __restrict__ tokIdx,
                  unsigned short* __restrict__ h, int nT) {
  __shared__ unsigned short LDSU[36864];  // 72 KiB = 3 x 24 KiB

  int total = gridDim.x;
  int L = blockIdx.x;
  int q = total >> 3, r8 = total & 7;
  int xcd = L & 7, idx = L >> 3;
  int work = (xcd < r8) ? (xcd * (q + 1) + idx) : (r8 * (q + 1) + (xcd - r8) * q + idx);
  int cb = work / nT;
  int tile = work - cb * nT;
  if (tile >= meta[0]) return;
  int e = tE[tile], base = tB[tile], valid = tV[tile];
  int tid = threadIdx.x;

  int w = tid >> 6, lane = tid & 63;
  int wr = w >> 2, wc = w & 3;
  int l15 = lane & 15, l4 = lane >> 4;
  int sr = lane >> 2, lch = lane & 3;

  const unsigned short* panel = w1t + (size_t)e * D_FF * D_MODEL;
  int rA = w * 16 + sr;
  int tokS = tokIdx[base + (rA < valid ? rA : valid - 1)];
  int gA = (lch - (rA >> 1)) & 3;
  const unsigned short* srcA0 = xb + (size_t)tokS * D_MODEL + gA * 8;
  int rB0 = w * 32 + sr;
  int gB0 = (lch - (rB0 >> 1)) & 3;
  const unsigned short* srcB0 = panel + (size_t)(cb * BN + rB0) * D_MODEL + gB0 * 8;
  int rB1 = w * 32 + 16 + sr;
  int gB1 = (lch - (rB1 >> 1)) & 3;
  const unsigned short* srcB1 = panel + (size_t)(cb * BN + rB1) * D_MODEL + gB1 * 8;

  ACC_INIT();
  PIPE3(D_MODEL / BK);  // 32

  #pragma unroll
  for (int n = 0; n < 4; n++) {
    int colc = cb * BN + wc * 64 + n * 16 + l15;
    float bias = b1[(size_t)e * D_FF + colc];
    #pragma unroll
    for (int m = 0; m < 4; m++) {
      #pragma unroll
      for (int r = 0; r < 4; r++) {
        int row = wr * 64 + m * 16 + l4 * 4 + r;
        float v = acc[m][n][r] + bias;
        v = v > 0.f ? v : 0.f;
        h[(size_t)(tile * BM + row) * D_FF + colc] = f2bf(v);
      }
    }
  }
}

// ---------------- GEMM2: out += w * (h @ W2 + b2)  (tile-major, 512 thr, BN=256) ----------------
__global__ __launch_bounds__(512)
void gemm2_kernel(const unsigned short* __restrict__ h,
                  const unsigned short* __restrict__ w2t,  // [e][D_MODEL][D_FF] bf16
                  const float* __restrict__ b2,
                  const int* __restrict__ meta,
                  const int* __restrict__ tE, const int* __restrict__ tB,
                  const int* __restrict__ tV, const int* __restrict__ tokIdx,
                  const float* __restrict__ tokW,
                  float* __restrict__ out) {
  __shared__ unsigned short LDSU[36864];  // 72 KiB

  int total = gridDim.x;
  int L = blockIdx.x;
  int q = total >> 3, r8 = total & 7;
  int xcd = L & 7, idx = L >> 3;
  int work = (xcd < r8) ? (xcd * (q + 1) + idx) : (r8 * (q + 1) + (xcd - r8) * q + idx);
  int tile = work >> 2;          // ncol = D_MODEL/BN = 4
  int cb = work & 3;
  if (tile >= meta[0]) return;
  int e = tE[tile], base = tB[tile], valid = tV[tile];
  int tid = threadIdx.x;

  int w = tid >> 6, lane = tid & 63;
  int wr = w >> 2, wc = w & 3;
  int l15 = lane & 15, l4 = lane >> 4;
  int sr = lane >> 2, lch = lane & 3;

  const unsigned short* panel = w2t + (size_t)e * D_MODEL * D_FF;
  int rA = w * 16 + sr;
  int gA = (lch - (rA >> 1)) & 3;
  const unsigned short* srcA0 = h + (size_t)(tile * BM + rA) * D_FF + gA * 8;
  int rB0 = w * 32 + sr;
  int gB0 = (lch - (rB0 >> 1)) & 3;
  const unsigned short* srcB0 = panel + (size_t)(cb * BN + rB0) * D_FF + gB0 * 8;
  int rB1 = w * 32 + 16 + sr;
  int gB1 = (lch - (rB1 >> 1)) & 3;
  const unsigned short* srcB1 = panel + (size_t)(cb * BN + rB1) * D_FF + gB1 * 8;

  ACC_INIT();
  PIPE3(D_FF / BK);  // 128

  float biasv[4];
  #pragma unroll
  for (int n = 0; n < 4; n++)
    biasv[n] = b2[(size_t)e * D_MODEL + cb * BN + wc * 64 + n * 16 + l15];

  #pragma unroll
  for (int m = 0; m < 4; m++) {
    #pragma unroll
    for (int r = 0; r < 4; r++) {
      int row = wr * 64 + m * 16 + l4 * 4 + r;
      if (row < valid) {
        int tok = tokIdx[base + row];
        float wgt = tokW[base + row];
        float* orow = out + (size_t)tok * D_MODEL + cb * BN + wc * 64 + l15;
        #pragma unroll
        for (int n = 0; n < 4; n++)
          atomicAdd(orow + n * 16, (acc[m][n][r] + biasv[n]) * wgt);
      }
    }
  }
}

// ---------------- host ----------------
extern "C" void kernel_launch(void* const* d_in, const int* in_sizes, int n_in,
                              void* d_out, int out_size, void* d_ws, size_t ws_size,
                              hipStream_t stream) {
  const float* x  = (const float*)d_in[0];
  const float* W1 = (const float*)d_in[1];
  const float* b1 = (const float*)d_in[2];
  const float* W2 = (const float*)d_in[3];
  const float* b2 = (const float*)d_in[4];
  const float* Wg = (const float*)d_in[5];
  const float* bg = (const float*)d_in[6];

  int T = in_sizes[0] / D_MODEL;  // 8192
  float* out = (float*)d_out;
  float* gate_out = out + (size_t)T * D_MODEL;

  char* ws = (char*)d_ws;
  int* cnt  = (int*)(ws + 0);
  int* meta = (int*)(ws + 64);
  int* tE   = (int*)(ws + 128);
  int* tB   = (int*)(ws + 1024);
  int* tV   = (int*)(ws + 2048);
  size_t off = 4096;
  int* tokIdx = (int*)(ws + off);   off += (size_t)N_EXP * T * 4;
  float* tokW = (float*)(ws + off); off += (size_t)N_EXP * T * 4;
  unsigned short* xb = (unsigned short*)(ws + off); off += (size_t)T * D_MODEL * 2;
  off = (off + 255) & ~(size_t)255;

  int maxTiles = (2 * T) / BM + N_EXP;  // 136

  unsigned short* w1t = (unsigned short*)(ws + off); off += (size_t)N_EXP * D_MODEL * D_FF * 2;
  unsigned short* w2t = (unsigned short*)(ws + off); off += (size_t)N_EXP * D_MODEL * D_FF * 2;
  unsigned short* h   = (unsigned short*)(ws + off);

  hipMemsetAsync(d_out, 0, (size_t)T * D_MODEL * sizeof(float), stream);
  hipMemsetAsync(cnt, 0, N_EXP * sizeof(int), stream);

  gating_kernel<<<(T + 3) / 4, 256, 0, stream>>>(x, Wg, bg, gate_out, xb, cnt, tokIdx, tokW, T);
  schedule_kernel<<<1, 64, 0, stream>>>(cnt, meta, tE, tB, tV, T, maxTiles);

  transpose_convert_all<<<4096, 256, 0, stream>>>(W1, W2, w1t, w2t);

  gemm1_kernel<<<maxTiles * (D_FF / BN), 512, 0, stream>>>(
      xb, w1t, b1, meta, tE, tB, tV, tokIdx, h, maxTiles);
  gemm2_kernel<<<maxTiles * (D_MODEL / BN), 512, 0, stream>>>(
      h, w2t, b2, meta, tE, tB, tV, tokIdx, tokW, out);
}